// Round 1
// baseline (82.117 us; speedup 1.0000x reference)
//
#include <hip/hip_runtime.h>
#include <stdint.h>

// Problem constants (from reference): T=2,000,000 tokens, VOCAB=4, D=128,
// N_READS=2000, segment_ids sorted ascending.
//
// Strategy: out[s][d] = (sum_v cnt[s][v] * E[v][d]) / max(sum_v cnt[s][v], 1)
// Phase 1: packed histogram counts[s] (4 x u16 lanes in one u64) via
//          run-length-aggregated global atomics (segment_ids sorted).
// Phase 2: 2000 x 128 weighted-sum emit.

#define TPB 256
#define TOK_PER_THREAD 32
#define DIM 128
#define VOCAB 4

__global__ __launch_bounds__(TPB) void seq_count_kernel(
    const int* __restrict__ tokens,
    const int* __restrict__ segs,
    unsigned long long* __restrict__ counts,
    int T) {
  const long long base =
      ((long long)blockIdx.x * TPB + threadIdx.x) * TOK_PER_THREAD;
  if (base >= T) return;

  int cur_seg = -1;
  unsigned long long acc = 0ULL;

  // Vectorized path: base is a multiple of 32 -> 16B-aligned int4 loads.
#pragma unroll
  for (int g = 0; g < TOK_PER_THREAD / 4; ++g) {
    const long long i = base + (long long)g * 4;
    if (i + 4 <= (long long)T) {
      const int4 tk = *(const int4*)(tokens + i);
      const int4 sg = *(const int4*)(segs + i);
      const int tks[4] = {tk.x, tk.y, tk.z, tk.w};
      const int sgs[4] = {sg.x, sg.y, sg.z, sg.w};
#pragma unroll
      for (int j = 0; j < 4; ++j) {
        const int s = sgs[j];
        if (s != cur_seg) {
          if (acc) atomicAdd(&counts[cur_seg], acc);
          cur_seg = s;
          acc = 0ULL;
        }
        acc += 1ULL << (16 * (tks[j] & 3));
      }
    } else {
      // Scalar tail (not hit for T % 32 == 0, kept for generality).
      for (long long k = i; k < (long long)T && k < i + 4; ++k) {
        const int s = segs[k];
        if (s != cur_seg) {
          if (acc) atomicAdd(&counts[cur_seg], acc);
          cur_seg = s;
          acc = 0ULL;
        }
        acc += 1ULL << (16 * (tokens[k] & 3));
      }
    }
  }
  if (acc && cur_seg >= 0) atomicAdd(&counts[cur_seg], acc);
}

__global__ __launch_bounds__(DIM) void seq_emit_kernel(
    const unsigned long long* __restrict__ counts,
    const float* __restrict__ emb,
    float* __restrict__ out) {
  const int seg = blockIdx.x;
  const int d = threadIdx.x;  // 0..127
  const unsigned long long c = counts[seg];
  const float c0 = (float)(unsigned)(c & 0xFFFFULL);
  const float c1 = (float)(unsigned)((c >> 16) & 0xFFFFULL);
  const float c2 = (float)(unsigned)((c >> 32) & 0xFFFFULL);
  const float c3 = (float)(unsigned)((c >> 48) & 0xFFFFULL);
  const float tot = fmaxf(c0 + c1 + c2 + c3, 1.0f);  // ref: max(counts, 1)
  const float v = c0 * emb[0 * DIM + d] + c1 * emb[1 * DIM + d] +
                  c2 * emb[2 * DIM + d] + c3 * emb[3 * DIM + d];
  out[(long long)seg * DIM + d] = v / tot;
}

extern "C" void kernel_launch(void* const* d_in, const int* in_sizes, int n_in,
                              void* d_out, int out_size, void* d_ws,
                              size_t ws_size, hipStream_t stream) {
  const int* tokens = (const int*)d_in[0];
  const int* segs = (const int*)d_in[1];
  const float* emb = (const float*)d_in[2];
  float* out = (float*)d_out;

  const int T = in_sizes[0];
  const int n_reads = out_size / DIM;  // 2000

  unsigned long long* counts = (unsigned long long*)d_ws;  // 16 KB needed

  // d_ws is poisoned (0xAA) before every timed launch — zero it first.
  hipMemsetAsync(counts, 0, (size_t)n_reads * sizeof(unsigned long long),
                 stream);

  const int tok_per_block = TPB * TOK_PER_THREAD;
  const int nblk = (int)(((long long)T + tok_per_block - 1) / tok_per_block);
  seq_count_kernel<<<nblk, TPB, 0, stream>>>(tokens, segs, counts, T);
  seq_emit_kernel<<<n_reads, DIM, 0, stream>>>(counts, emb, out);
}

// Round 2
// 71.469 us; speedup vs baseline: 1.1490x; 1.1490x over previous
//
#include <hip/hip_runtime.h>
#include <stdint.h>

// T=2,000,000 tokens, VOCAB=4, D=128, N_READS=2000, segment_ids SORTED.
//
// out[s][d] = (sum_v cnt[s][v] * E[v][d]) / max(sum_v cnt[s][v], 1)
//
// One kernel, one block per segment:
//   1. wave-parallel 64-ary lower_bound on sorted segs for [s, s+1) bounds
//      (waves 0 and 1 search in parallel; ~4 probe rounds each)
//   2. stream tokens[lo..hi) coalesced, histogram packed in u64 (4 x u16)
//   3. shuffle + LDS reduce, emit weighted mean for 128 dims
// No workspace, no memset, no global atomics, single graph node.

#define DIM 128
#define TPB 256

__device__ __forceinline__ int wave_lower_bound(const int* __restrict__ a,
                                                int n, int t) {
  const int lane = threadIdx.x & 63;
  int lo = 0, hi = n;  // answer (first idx with a[idx] >= t) is in [lo, hi]
  while (hi - lo > 64) {
    const long long span = hi - lo;
    const int idx = lo + (int)((span * (lane + 1)) >> 6);  // lane63 -> hi
    const int probe = (idx < hi) ? a[idx] : 0x7fffffff;    // a[hi] = +inf
    const unsigned long long mask = __ballot(probe >= t);
    const int first = __ffsll(mask) - 1;  // mask != 0 (lane63 true)
    const int nlo = (first == 0) ? lo : lo + (int)((span * (long long)first) >> 6);
    const int nhi = lo + (int)((span * (long long)(first + 1)) >> 6);
    lo = nlo;
    hi = nhi;
  }
  const int idx = lo + lane;
  const bool ge = (idx < hi) ? (a[idx] >= t) : true;
  const unsigned long long mask = __ballot(ge);
  return lo + __ffsll(mask) - 1;
}

__global__ __launch_bounds__(TPB) void seg_mean_kernel(
    const int* __restrict__ tokens, const int* __restrict__ segs,
    const float* __restrict__ emb, float* __restrict__ out, int T) {
  const int s = blockIdx.x;
  const int tid = threadIdx.x;
  const int wave = tid >> 6;

  __shared__ int bounds[2];
  __shared__ unsigned long long red[TPB / 64];

  if (wave < 2) {
    const int r = wave_lower_bound(segs, T, s + wave);
    if ((tid & 63) == 0) bounds[wave] = r;
  }
  __syncthreads();
  const int lo = bounds[0];
  const int hi = bounds[1];

  // Packed histogram: u64 as 4 x u16 lanes (per-thread <= ~5 per lane,
  // per-wave <= ~320, per-block <= ~1300 -- no u16 overflow).
  unsigned long long acc = 0ULL;
  for (int i = lo + tid; i < hi; i += TPB) {
    acc += 1ULL << ((tokens[i] & 3) << 4);
  }

#pragma unroll
  for (int off = 32; off > 0; off >>= 1) {
    acc += __shfl_down(acc, off, 64);
  }
  if ((tid & 63) == 0) red[wave] = acc;
  __syncthreads();
  if (tid == 0) {
    red[0] = red[0] + red[1] + red[2] + red[3];
  }
  __syncthreads();

  const unsigned long long c = red[0];
  if (tid < DIM) {
    const float c0 = (float)(unsigned)(c & 0xFFFFULL);
    const float c1 = (float)(unsigned)((c >> 16) & 0xFFFFULL);
    const float c2 = (float)(unsigned)((c >> 32) & 0xFFFFULL);
    const float c3 = (float)(unsigned)((c >> 48) & 0xFFFFULL);
    const float tot = fmaxf(c0 + c1 + c2 + c3, 1.0f);  // ref: max(counts, 1)
    const float v = c0 * emb[tid] + c1 * emb[DIM + tid] +
                    c2 * emb[2 * DIM + tid] + c3 * emb[3 * DIM + tid];
    out[(long long)s * DIM + tid] = v / tot;
  }
}

extern "C" void kernel_launch(void* const* d_in, const int* in_sizes, int n_in,
                              void* d_out, int out_size, void* d_ws,
                              size_t ws_size, hipStream_t stream) {
  const int* tokens = (const int*)d_in[0];
  const int* segs = (const int*)d_in[1];
  const float* emb = (const float*)d_in[2];
  float* out = (float*)d_out;

  const int T = in_sizes[0];
  const int n_reads = out_size / DIM;  // 2000

  seg_mean_kernel<<<n_reads, TPB, 0, stream>>>(tokens, segs, emb, out, T);
}